// Round 7
// baseline (238.901 us; speedup 1.0000x reference)
//
#include <hip/hip_runtime.h>
#include <hip/hip_bf16.h>

// Chamfer via MFMA, SINGLE-SWEEP dual reduction: the 8192x8192 distance
// matrix P[n,m] = |gts_n - preds_m|^2 is computed ONCE per batch; row-mins
// (loss_2) and col-mins (loss_1) both extracted from the same MFMA tiles.
//   a(x) = [xh0..2, xl0..2, xh0..2, 1, 1, xxh, xxl, 0,0,0]       (A = gts rows)
//   b(y) = [-2yh0..2, -2yh0..2, -2yl0..2, yyh, yyl, 1, 1, 0,0,0] (B = preds cols)
// C layout (32x32, verified m74/m101): col=lane&31 -> B point (pred),
// row=(r&3)+8*(r>>2)+4*kh -> A point (gt).
// Block: 512 rows x 1024 cols; 8 waves each own 64 rows (2 A-frags resident),
// sweep 32 col-tiles from LDS (staged once). Per MFMA: 16 row-folds (min3)
// + min3-tree 16->1 + kh shfl-fold -> LDS atomicMin colcomb.
// Block end: shfl-fold row mins, global int atomicMin into minarr[2][8][8192].

typedef _Float16 f16x8 __attribute__((ext_vector_type(8)));
typedef float f32x16 __attribute__((ext_vector_type(16)));

#define NPTS 8192
#define BATCH 8
#define TPB 512
#define BR 512                      // rows per block
#define BC 1024                     // cols per block
#define CT (BC / 32)                // 32 col-tiles
#define T_R 2                       // row-frags per wave
#define NQ_TOT (2 * BATCH * NPTS)   // 131072

__device__ __forceinline__ void cvt_split(float v, _Float16& h, _Float16& l) {
    h = (_Float16)v; l = (_Float16)(v - (float)h);
}

__device__ __forceinline__ void aform(float x0, float x1, float x2,
                                      f16x8& lo, f16x8& hi) {
    _Float16 h0, l0, h1, l1, h2, l2;
    cvt_split(x0, h0, l0); cvt_split(x1, h1, l1); cvt_split(x2, h2, l2);
    const float xx = x0 * x0 + x1 * x1 + x2 * x2;
    _Float16 xxh, xxl; cvt_split(xx, xxh, xxl);
    lo = f16x8{ h0, h1, h2, l0, l1, l2, h0, h1 };
    hi = f16x8{ h2, (_Float16)1, (_Float16)1, xxh, xxl,
                (_Float16)0, (_Float16)0, (_Float16)0 };
}

__device__ __forceinline__ void bform(float y0, float y1, float y2,
                                      f16x8& lo, f16x8& hi) {
    _Float16 h0, l0, h1, l1, h2, l2;
    { const float hf = (float)(_Float16)y0; h0 = (_Float16)(-2.f * hf); l0 = (_Float16)(-2.f * (y0 - hf)); }
    { const float hf = (float)(_Float16)y1; h1 = (_Float16)(-2.f * hf); l1 = (_Float16)(-2.f * (y1 - hf)); }
    { const float hf = (float)(_Float16)y2; h2 = (_Float16)(-2.f * hf); l2 = (_Float16)(-2.f * (y2 - hf)); }
    const float yy = y0 * y0 + y1 * y1 + y2 * y2;
    _Float16 yyh, yyl; cvt_split(yy, yyh, yyl);
    lo = f16x8{ h0, h1, h2, h0, h1, h2, l0, l1 };
    hi = f16x8{ l2, yyh, yyl, (_Float16)1, (_Float16)1,
                (_Float16)0, (_Float16)0, (_Float16)0 };
}

// 16 -> 1 min, min3-shaped (fminf(fminf(a,b),c) fuses to v_min3_f32), depth 3.
__device__ __forceinline__ float min16(const f32x16 a) {
    const float t0 = fminf(fminf(a[0],  a[1]),  a[2]);
    const float t1 = fminf(fminf(a[3],  a[4]),  a[5]);
    const float t2 = fminf(fminf(a[6],  a[7]),  a[8]);
    const float t3 = fminf(fminf(a[9],  a[10]), a[11]);
    const float t4 = fminf(fminf(a[12], a[13]), a[14]);
    const float u0 = fminf(fminf(t0, t1), t2);
    const float u1 = fminf(fminf(t3, t4), a[15]);
    return fminf(u0, u1);
}

__global__ __launch_bounds__(TPB, 4) void chamfer_mfma_kernel(
    const float* __restrict__ preds, const float* __restrict__ gts,
    int* __restrict__ minarr /* [2][BATCH][NPTS] int-bits of f32, 0x7f-init */)
{
    __shared__ f16x8 ldsB[CT][2][32];   // 32 KB
    __shared__ int colcomb[BC];         // 4 KB

    const int bid    = blockIdx.x;      // 1024 blocks
    const int b      = bid >> 7;        // 8
    const int rowblk = (bid >> 3) & 15; // 16
    const int colblk = bid & 7;         // 8

    const float* __restrict__ Gb = gts   + (size_t)b * NPTS * 3;
    const float* __restrict__ Pb = preds + (size_t)b * NPTS * 3;

    const int tid  = threadIdx.x;
    const int lane = tid & 63;
    const int w    = tid >> 6;          // 8 waves
    const int kh   = lane >> 5;
    const int cl   = lane & 31;

    // init colcomb
    colcomb[tid]       = 0x7f7f7f7f;
    colcomb[tid + 512] = 0x7f7f7f7f;

    // stage B (preds cols) into LDS: 2 points per thread
#pragma unroll
    for (int i = 0; i < BC / TPB; ++i) {
        const int pl = i * TPB + tid;
        const float* yp = Pb + (size_t)(colblk * BC + pl) * 3;
        f16x8 lo, hi; bform(yp[0], yp[1], yp[2], lo, hi);
        ldsB[pl >> 5][0][pl & 31] = lo;
        ldsB[pl >> 5][1][pl & 31] = hi;
    }

    // A fragments: this wave's 64 rows (gts), resident
    f16x8 af[T_R];
#pragma unroll
    for (int t = 0; t < T_R; ++t) {
        const int row = rowblk * BR + w * 64 + t * 32 + cl;
        const float* xp = Gb + (size_t)row * 3;
        f16x8 lo, hi; aform(xp[0], xp[1], xp[2], lo, hi);
        af[t] = kh ? hi : lo;
    }

    const f32x16 zc = {};
    float rbRow[T_R][16];
#pragma unroll
    for (int t = 0; t < T_R; ++t)
#pragma unroll
        for (int r = 0; r < 16; ++r) rbRow[t][r] = 1e30f;

    __syncthreads();

    const f16x8* __restrict__ bbase = &ldsB[0][kh][cl];
#pragma unroll 2
    for (int ct = 0; ct < CT; ct += 2) {
        const f16x8 b0 = bbase[ct * 64];
        const f16x8 b1 = bbase[(ct + 1) * 64];
#pragma unroll
        for (int t = 0; t < T_R; ++t) {
            const f32x16 m0 = __builtin_amdgcn_mfma_f32_32x32x16_f16(af[t], b0, zc, 0, 0, 0);
            const f32x16 m1 = __builtin_amdgcn_mfma_f32_32x32x16_f16(af[t], b1, zc, 0, 0, 0);
            // row side: fold both tiles into running row-mins (min3-shaped)
#pragma unroll
            for (int r = 0; r < 16; ++r)
                rbRow[t][r] = fminf(fminf(m0[r], m1[r]), rbRow[t][r]);
            // col side: tree to one scalar per lane, fold kh halves, LDS min
            float v0 = min16(m0);
            float v1 = min16(m1);
            v0 = fminf(v0, __shfl_xor(v0, 32, 64));
            v1 = fminf(v1, __shfl_xor(v1, 32, 64));
            if (t == T_R - 1 && kh == 0) {
                atomicMin(&colcomb[ct * 32 + cl],       __float_as_int(v0));
                atomicMin(&colcomb[(ct + 1) * 32 + cl], __float_as_int(v1));
            } else if (t < T_R - 1) {
                // combine t=0 into t=1's pass via registers: stash in rbRow? no —
                // simpler: every t does its own LDS atomicMin (min is assoc.)
                if (kh == 0) {
                    atomicMin(&colcomb[ct * 32 + cl],       __float_as_int(v0));
                    atomicMin(&colcomb[(ct + 1) * 32 + cl], __float_as_int(v1));
                }
            }
        }
    }

    // --- row epilogue: fold across the 32 col-lanes, then global atomicMin ---
#pragma unroll
    for (int t = 0; t < T_R; ++t)
#pragma unroll
        for (int r = 0; r < 16; ++r) {
            float v = rbRow[t][r];
            v = fminf(v, __shfl_xor(v, 1, 64));
            v = fminf(v, __shfl_xor(v, 2, 64));
            v = fminf(v, __shfl_xor(v, 4, 64));
            v = fminf(v, __shfl_xor(v, 8, 64));
            v = fminf(v, __shfl_xor(v, 16, 64));
            rbRow[t][r] = v;
        }
    if (cl == 0) {
        int* rowdst = minarr + (BATCH + b) * NPTS + rowblk * BR + w * 64;
#pragma unroll
        for (int t = 0; t < T_R; ++t)
#pragma unroll
            for (int r = 0; r < 16; ++r) {
                const int rloc = (r & 3) + 8 * (r >> 2) + 4 * kh;
                atomicMin(&rowdst[t * 32 + rloc], __float_as_int(rbRow[t][r]));
            }
    }

    // --- col epilogue: block's col-mins -> global atomicMin ---
    __syncthreads();
    int* coldst = minarr + b * NPTS + colblk * BC;
#pragma unroll
    for (int i = 0; i < BC / TPB; ++i)
        atomicMin(&coldst[i * TPB + tid], colcomb[i * TPB + tid]);
}

// Stage 2: sum 131072 final mins -> 512 block sums
__global__ __launch_bounds__(256) void chamfer_reduce1(
    const float* __restrict__ minarr, float* __restrict__ bsums)
{
    const int gid = blockIdx.x * 256 + threadIdx.x;
    float m = minarr[gid];
#pragma unroll
    for (int off = 32; off > 0; off >>= 1) m += __shfl_down(m, off, 64);

    __shared__ float wsum[4];
    const int lane = threadIdx.x & 63;
    const int wid  = threadIdx.x >> 6;
    if (lane == 0) wsum[wid] = m;
    __syncthreads();
    if (threadIdx.x == 0)
        bsums[blockIdx.x] = (wsum[0] + wsum[1]) + (wsum[2] + wsum[3]);
}

// Stage 3: sum 512 block sums, scale, write scalar
__global__ __launch_bounds__(512) void chamfer_reduce2(
    const float* __restrict__ bsums, float* __restrict__ out)
{
    float m = bsums[threadIdx.x];
#pragma unroll
    for (int off = 32; off > 0; off >>= 1) m += __shfl_down(m, off, 64);

    __shared__ float wsum[8];
    const int lane = threadIdx.x & 63;
    const int wid  = threadIdx.x >> 6;
    if (lane == 0) wsum[wid] = m;
    __syncthreads();
    if (threadIdx.x == 0) {
        float t = ((wsum[0] + wsum[1]) + (wsum[2] + wsum[3]))
                + ((wsum[4] + wsum[5]) + (wsum[6] + wsum[7]));
        out[0] = t * (1.0f / 65536.0f);
    }
}

extern "C" void kernel_launch(void* const* d_in, const int* in_sizes, int n_in,
                              void* d_out, int out_size, void* d_ws, size_t ws_size,
                              hipStream_t stream) {
    const float* preds = (const float*)d_in[0];   // [8, 8192, 3]
    const float* gts   = (const float*)d_in[1];   // [8, 8192, 3]
    float* out = (float*)d_out;

    int*   minarr = (int*)d_ws;      // 131072 ints = 512 KB
    float* bsums  = (float*)((char*)d_ws + (size_t)NQ_TOT * sizeof(int));

    // 0x7f7f7f7f == 3.39e38f: "+inf" for int-cast float atomicMin (d2 >= ~0).
    hipMemsetAsync(minarr, 0x7f, (size_t)NQ_TOT * sizeof(int), stream);

    chamfer_mfma_kernel<<<1024, TPB, 0, stream>>>(preds, gts, minarr);
    chamfer_reduce1<<<512, 256, 0, stream>>>((const float*)minarr, bsums);
    chamfer_reduce2<<<1, 512, 0, stream>>>(bsums, out);
}

// Round 8
// 51.657 us; speedup vs baseline: 4.6247x; 4.6247x over previous
//
#include <hip/hip_runtime.h>
#include <hip/hip_bf16.h>

// Chamfer via MFMA, SINGLE-SWEEP dual reduction, PLAIN-STORE partials.
// P[n,m] = |gts_n - preds_m|^2 computed ONCE per batch; row-mins (loss_2)
// and col-mins (loss_1) extracted from the same MFMA tiles.
//   a(x) = [xh0..2, xl0..2, xh0..2, 1, 1, xxh, xxl, 0,0,0]       (A = gts rows)
//   b(y) = [-2yh0..2, -2yh0..2, -2yl0..2, yyh, yyl, 1, 1, 0,0,0] (B = preds cols)
// C layout (verified R3/R5/R6): col=lane&31 -> pred, row=(r&3)+8*(r>>2)+4*kh -> gt.
// Block = 512 gts-rows x 1024 preds-cols. Row-mins: register fold + shfl,
// exclusive slot rowpart[b][row][colblk] (plain store). Col-mins: min3-tree
// 32->1 per tile + LDS atomicMin, then plain store colpart[..][col][rowblk].
// R7 lesson: NO global atomics (1.5M contended atomicMins = 1.1 GB HBM traffic).

typedef _Float16 f16x8 __attribute__((ext_vector_type(8)));
typedef float f32x16 __attribute__((ext_vector_type(16)));

#define NPTS 8192
#define BATCH 8
#define TPB 512
#define BR 512                      // rows per block
#define BC 1024                     // cols per block
#define CT (BC / 32)                // 32 col-tiles
#define NROWBLK (NPTS / BR)         // 16
#define NCOLBLK (NPTS / BC)         // 8

__device__ __forceinline__ void cvt_split(float v, _Float16& h, _Float16& l) {
    h = (_Float16)v; l = (_Float16)(v - (float)h);
}

__device__ __forceinline__ void aform(float x0, float x1, float x2,
                                      f16x8& lo, f16x8& hi) {
    _Float16 h0, l0, h1, l1, h2, l2;
    cvt_split(x0, h0, l0); cvt_split(x1, h1, l1); cvt_split(x2, h2, l2);
    const float xx = x0 * x0 + x1 * x1 + x2 * x2;
    _Float16 xxh, xxl; cvt_split(xx, xxh, xxl);
    lo = f16x8{ h0, h1, h2, l0, l1, l2, h0, h1 };
    hi = f16x8{ h2, (_Float16)1, (_Float16)1, xxh, xxl,
                (_Float16)0, (_Float16)0, (_Float16)0 };
}

__device__ __forceinline__ void bform(float y0, float y1, float y2,
                                      f16x8& lo, f16x8& hi) {
    _Float16 h0, l0, h1, l1, h2, l2;
    { const float hf = (float)(_Float16)y0; h0 = (_Float16)(-2.f * hf); l0 = (_Float16)(-2.f * (y0 - hf)); }
    { const float hf = (float)(_Float16)y1; h1 = (_Float16)(-2.f * hf); l1 = (_Float16)(-2.f * (y1 - hf)); }
    { const float hf = (float)(_Float16)y2; h2 = (_Float16)(-2.f * hf); l2 = (_Float16)(-2.f * (y2 - hf)); }
    const float yy = y0 * y0 + y1 * y1 + y2 * y2;
    _Float16 yyh, yyl; cvt_split(yy, yyh, yyl);
    lo = f16x8{ h0, h1, h2, h0, h1, h2, l0, l1 };
    hi = f16x8{ l2, yyh, yyl, (_Float16)1, (_Float16)1,
                (_Float16)0, (_Float16)0, (_Float16)0 };
}

__device__ __forceinline__ float min3h(float a, float b, float c) {
    return fminf(fminf(a, b), c);   // clang fuses to v_min3_f32
}

// min over 32 values (two acc vectors), min3-shaped: 17 ops, depth 4.
__device__ __forceinline__ float min32(const f32x16 a, const f32x16 b) {
    const float m0 = min3h(a[0],  a[1],  a[2]);
    const float m1 = min3h(a[3],  a[4],  a[5]);
    const float m2 = min3h(a[6],  a[7],  a[8]);
    const float m3 = min3h(a[9],  a[10], a[11]);
    const float m4 = min3h(a[12], a[13], a[14]);
    const float m5 = min3h(a[15], b[0],  b[1]);
    const float m6 = min3h(b[2],  b[3],  b[4]);
    const float m7 = min3h(b[5],  b[6],  b[7]);
    const float m8 = min3h(b[8],  b[9],  b[10]);
    const float m9 = min3h(b[11], b[12], b[13]);
    const float m10 = fminf(b[14], b[15]);
    const float n0 = min3h(m0, m1, m2);
    const float n1 = min3h(m3, m4, m5);
    const float n2 = min3h(m6, m7, m8);
    const float n3 = fminf(m9, m10);
    return fminf(min3h(n0, n1, n2), n3);
}

__global__ __launch_bounds__(TPB, 2) void chamfer_sweep_kernel(
    const float* __restrict__ preds, const float* __restrict__ gts,
    float* __restrict__ colpart /* [B*NCOLBLK*BC][NROWBLK] */,
    float* __restrict__ rowpart /* [B*NPTS][NCOLBLK] */)
{
    __shared__ f16x8 ldsB[CT][2][32];   // 32 KB
    __shared__ int colcomb[BC];         // 4 KB

    const int bid    = blockIdx.x;      // 1024 blocks
    const int b      = bid >> 7;        // 8
    const int rowblk = (bid >> 3) & 15; // 16
    const int colblk = bid & 7;         // 8

    const float* __restrict__ Gb = gts   + (size_t)b * NPTS * 3;
    const float* __restrict__ Pb = preds + (size_t)b * NPTS * 3;

    const int tid  = threadIdx.x;
    const int lane = tid & 63;
    const int w    = tid >> 6;          // 8 waves
    const int kh   = lane >> 5;
    const int cl   = lane & 31;

    colcomb[tid]       = 0x7f7f7f7f;    // 3.39e38f
    colcomb[tid + 512] = 0x7f7f7f7f;

    // stage B (preds cols) into LDS: 2 points per thread
#pragma unroll
    for (int i = 0; i < BC / TPB; ++i) {
        const int pl = i * TPB + tid;
        const float* yp = Pb + (size_t)(colblk * BC + pl) * 3;
        f16x8 lo, hi; bform(yp[0], yp[1], yp[2], lo, hi);
        ldsB[pl >> 5][0][pl & 31] = lo;
        ldsB[pl >> 5][1][pl & 31] = hi;
    }

    // A fragments: this wave's 64 rows (gts), resident
    f16x8 af[2];
#pragma unroll
    for (int t = 0; t < 2; ++t) {
        const int row = rowblk * BR + w * 64 + t * 32 + cl;
        const float* xp = Gb + (size_t)row * 3;
        f16x8 lo, hi; aform(xp[0], xp[1], xp[2], lo, hi);
        af[t] = kh ? hi : lo;
    }

    const f32x16 zc = {};
    float rbRow[2][16];
#pragma unroll
    for (int t = 0; t < 2; ++t)
#pragma unroll
        for (int r = 0; r < 16; ++r) rbRow[t][r] = 1e30f;

    __syncthreads();

    const f16x8* __restrict__ bbase = &ldsB[0][kh][cl];
#pragma unroll 2
    for (int ct = 0; ct < CT; ++ct) {
        const f16x8 bf = bbase[ct * 64];
        const f32x16 a0 = __builtin_amdgcn_mfma_f32_32x32x16_f16(af[0], bf, zc, 0, 0, 0);
        const f32x16 a1 = __builtin_amdgcn_mfma_f32_32x32x16_f16(af[1], bf, zc, 0, 0, 0);
        // row side: fold into running row-mins
#pragma unroll
        for (int r = 0; r < 16; ++r) rbRow[0][r] = fminf(a0[r], rbRow[0][r]);
#pragma unroll
        for (int r = 0; r < 16; ++r) rbRow[1][r] = fminf(a1[r], rbRow[1][r]);
        // col side: 32 rows -> 1 per lane-col, fold kh halves, LDS atomic
        float v = min32(a0, a1);
        v = fminf(v, __shfl_xor(v, 32, 64));
        if (kh == 0)
            atomicMin(&colcomb[ct * 32 + cl], __float_as_int(v));
    }

    // --- row epilogue: fold across 32 col-lanes, plain store (exclusive slot) ---
#pragma unroll
    for (int t = 0; t < 2; ++t)
#pragma unroll
        for (int r = 0; r < 16; ++r) {
            float v = rbRow[t][r];
            v = fminf(v, __shfl_xor(v, 1, 64));
            v = fminf(v, __shfl_xor(v, 2, 64));
            v = fminf(v, __shfl_xor(v, 4, 64));
            v = fminf(v, __shfl_xor(v, 8, 64));
            v = fminf(v, __shfl_xor(v, 16, 64));
            rbRow[t][r] = v;
        }
    if (cl == 0) {
        const size_t rowbase = (size_t)b * NPTS + rowblk * BR + w * 64;
#pragma unroll
        for (int t = 0; t < 2; ++t)
#pragma unroll
            for (int r = 0; r < 16; ++r) {
                const int rloc = (r & 3) + 8 * (r >> 2) + 4 * kh;
                rowpart[(rowbase + t * 32 + rloc) * NCOLBLK + colblk] = rbRow[t][r];
            }
    }

    // --- col epilogue: block col-mins -> plain store (exclusive slot) ---
    __syncthreads();
#pragma unroll
    for (int i = 0; i < BC / TPB; ++i) {
        const int col = i * TPB + tid;
        const size_t cq = (size_t)(b * NCOLBLK + colblk) * BC + col;
        colpart[cq * NROWBLK + rowblk] = __int_as_float(colcomb[col]);
    }
}

// Stage 2: fold partials per query, sum -> 512 block sums.
// gid < 65536: preds side (16 slots); else gts side (8 slots).
__global__ __launch_bounds__(256) void chamfer_reduce1(
    const float* __restrict__ colpart, const float* __restrict__ rowpart,
    float* __restrict__ bsums)
{
    const int gid = blockIdx.x * 256 + threadIdx.x;
    float m;
    if (gid < 65536) {
        const float4* p = (const float4*)(colpart + (size_t)gid * 16);
        const float4 q0 = p[0], q1 = p[1], q2 = p[2], q3 = p[3];
        const float u0 = fminf(fminf(q0.x, q0.y), fminf(q0.z, q0.w));
        const float u1 = fminf(fminf(q1.x, q1.y), fminf(q1.z, q1.w));
        const float u2 = fminf(fminf(q2.x, q2.y), fminf(q2.z, q2.w));
        const float u3 = fminf(fminf(q3.x, q3.y), fminf(q3.z, q3.w));
        m = fminf(fminf(u0, u1), fminf(u2, u3));
    } else {
        const float4* p = (const float4*)(rowpart + (size_t)(gid - 65536) * 8);
        const float4 q0 = p[0], q1 = p[1];
        m = fminf(fminf(fminf(q0.x, q0.y), fminf(q0.z, q0.w)),
                  fminf(fminf(q1.x, q1.y), fminf(q1.z, q1.w)));
    }

#pragma unroll
    for (int off = 32; off > 0; off >>= 1) m += __shfl_down(m, off, 64);

    __shared__ float wsum[4];
    const int lane = threadIdx.x & 63;
    const int wid  = threadIdx.x >> 6;
    if (lane == 0) wsum[wid] = m;
    __syncthreads();
    if (threadIdx.x == 0)
        bsums[blockIdx.x] = (wsum[0] + wsum[1]) + (wsum[2] + wsum[3]);
}

// Stage 3: sum 512 block sums, scale, write scalar
__global__ __launch_bounds__(512) void chamfer_reduce2(
    const float* __restrict__ bsums, float* __restrict__ out)
{
    float m = bsums[threadIdx.x];
#pragma unroll
    for (int off = 32; off > 0; off >>= 1) m += __shfl_down(m, off, 64);

    __shared__ float wsum[8];
    const int lane = threadIdx.x & 63;
    const int wid  = threadIdx.x >> 6;
    if (lane == 0) wsum[wid] = m;
    __syncthreads();
    if (threadIdx.x == 0) {
        float t = ((wsum[0] + wsum[1]) + (wsum[2] + wsum[3]))
                + ((wsum[4] + wsum[5]) + (wsum[6] + wsum[7]));
        out[0] = t * (1.0f / 65536.0f);
    }
}

extern "C" void kernel_launch(void* const* d_in, const int* in_sizes, int n_in,
                              void* d_out, int out_size, void* d_ws, size_t ws_size,
                              hipStream_t stream) {
    const float* preds = (const float*)d_in[0];   // [8, 8192, 3]
    const float* gts   = (const float*)d_in[1];   // [8, 8192, 3]
    float* out = (float*)d_out;

    float* colpart = (float*)d_ws;                                 // 4 MB
    float* rowpart = (float*)((char*)d_ws + (size_t)65536 * 16 * sizeof(float));  // 2 MB
    float* bsums   = (float*)((char*)d_ws + (size_t)(65536 * 16 + 65536 * 8) * sizeof(float));

    chamfer_sweep_kernel<<<1024, TPB, 0, stream>>>(preds, gts, colpart, rowpart);
    chamfer_reduce1<<<512, 256, 0, stream>>>(colpart, rowpart, bsums);
    chamfer_reduce2<<<1, 512, 0, stream>>>(bsums, out);
}

// Round 9
// 48.593 us; speedup vs baseline: 4.9163x; 1.0630x over previous
//
#include <hip/hip_runtime.h>
#include <hip/hip_bf16.h>

// Chamfer via MFMA: D = |x_n - y_m|^2 as augmented K=16 fp16-split GEMM,
// TWO-PASS (rows=outputs in regs, cols staged in LDS; pass 1 swaps roles).
//   a(x) = [xh0..2, xl0..2, xh0..2, 1, 1, xxh, xxl, 0,0,0]
//   b(y) = [-2yh0..2, -2yh0..2, -2yl0..2, yyh, yyl, 1, 1, 0,0,0]
// C layout (verified R3/R5): col=lane&31 -> B pt, row=(r&3)+8*(r>>2)+4*kh -> A pt.
// R9 = R5 structure at TPB=256 / grid=1024 / __launch_bounds__(256,4):
// 4 blocks/CU, 16 waves/CU (was ~3 waves/SIMD) to close the 2x stall gap
// (R5: VALUBusy 47 + MfmaUtil 31, neither saturated). Fold: 16 min3 per
// 2 col-tiles (one min-op per distance = the VALU floor).

typedef _Float16 f16x8 __attribute__((ext_vector_type(8)));
typedef float f32x16 __attribute__((ext_vector_type(16)));

#define NPTS 8192
#define BATCH 8
#define TPB 256
#define BN 256                      // rows per block (4 waves x 2 rowtiles x 32)
#define BM 1024                     // cols staged per LDS chunk
#define CPB 4                       // chunks per block (half the col space)
#define CTPC (BM / 32)              // 32 col-tiles per chunk
#define NQ_TOT (2 * BATCH * NPTS)   // 131072

__device__ __forceinline__ void cvt_split(float v, _Float16& h, _Float16& l) {
    h = (_Float16)v; l = (_Float16)(v - (float)h);
}

__global__ __launch_bounds__(TPB, 4) void chamfer_mfma_kernel(
    const float* __restrict__ preds, const float* __restrict__ gts,
    float* __restrict__ partial /* [2][BATCH][NPTS][2] */)
{
    __shared__ f16x8 ldsB[CTPC][2][32];   // 32 KB

    const int bid  = blockIdx.x;          // 1024 blocks
    const int pass = bid >> 9;
    const int b       = (bid >> 6) & 7;
    const int rowblk  = (bid >> 1) & 31;  // 32 row-blocks (8192/256)
    const int colhalf = bid & 1;

    const float* __restrict__ Asrc = (pass == 0) ? gts : preds;
    const float* __restrict__ Bsrc = (pass == 0) ? preds : gts;
    const float* __restrict__ Ab = Asrc + (size_t)b * NPTS * 3;
    const float* __restrict__ Bb = Bsrc + (size_t)b * NPTS * 3;

    const int tid  = threadIdx.x;
    const int lane = tid & 63;
    const int w    = tid >> 6;        // 4 waves
    const int kh   = lane >> 5;       // k-half
    const int cl   = lane & 31;       // row (A) / col (B) within tile

    // --- A fragments (2 row-tiles per wave) ---
    f16x8 af[2];
#pragma unroll
    for (int t = 0; t < 2; ++t) {
        const int row = rowblk * BN + w * 64 + t * 32 + cl;
        const float* xp = Ab + (size_t)row * 3;
        const float x0 = xp[0], x1 = xp[1], x2 = xp[2];
        _Float16 h0, l0, h1, l1, h2, l2;
        cvt_split(x0, h0, l0); cvt_split(x1, h1, l1); cvt_split(x2, h2, l2);
        const float xx = x0 * x0 + x1 * x1 + x2 * x2;
        _Float16 xxh, xxl; cvt_split(xx, xxh, xxl);
        const f16x8 lo = { h0, h1, h2, l0, l1, l2, h0, h1 };
        const f16x8 hi = { h2, (_Float16)1, (_Float16)1, xxh, xxl,
                           (_Float16)0, (_Float16)0, (_Float16)0 };
        af[t] = kh ? hi : lo;
    }

    const f16x8* __restrict__ bptr = &ldsB[0][kh][cl];
    const f32x16 zc = {};

    float rb[2][16];
#pragma unroll
    for (int t = 0; t < 2; ++t)
#pragma unroll
        for (int r = 0; r < 16; ++r) rb[t][r] = 1e30f;

    for (int chunk = 0; chunk < CPB; ++chunk) {
        const int cbase = (colhalf * CPB + chunk) * BM;
        __syncthreads();
        // --- stage+convert BM cols into LDS (4 points per thread) ---
#pragma unroll
        for (int i = 0; i < BM / TPB; ++i) {
            const int pl = i * TPB + tid;
            const float* yp = Bb + (size_t)(cbase + pl) * 3;
            const float y0 = yp[0], y1 = yp[1], y2 = yp[2];
            _Float16 nh0, nl0, nh1, nl1, nh2, nl2;
            { const float hf = (float)(_Float16)y0; nh0 = (_Float16)(-2.f * hf); nl0 = (_Float16)(-2.f * (y0 - hf)); }
            { const float hf = (float)(_Float16)y1; nh1 = (_Float16)(-2.f * hf); nl1 = (_Float16)(-2.f * (y1 - hf)); }
            { const float hf = (float)(_Float16)y2; nh2 = (_Float16)(-2.f * hf); nl2 = (_Float16)(-2.f * (y2 - hf)); }
            const float yy = y0 * y0 + y1 * y1 + y2 * y2;
            _Float16 yyh, yyl; cvt_split(yy, yyh, yyl);
            const f16x8 lo = { nh0, nh1, nh2, nh0, nh1, nh2, nl0, nl1 };
            const f16x8 hi = { nl2, yyh, yyl, (_Float16)1, (_Float16)1,
                               (_Float16)0, (_Float16)0, (_Float16)0 };
            ldsB[pl >> 5][0][pl & 31] = lo;
            ldsB[pl >> 5][1][pl & 31] = hi;
        }
        __syncthreads();

        // --- sweep col-tile PAIRS: 2 ds_read -> 4 MFMA -> 32 min3 ---
#pragma unroll 2
        for (int ct = 0; ct < CTPC; ct += 2) {
            const f16x8 bfA = bptr[ct * 64];
            const f16x8 bfB = bptr[(ct + 1) * 64];
#pragma unroll
            for (int t = 0; t < 2; ++t) {
                const f32x16 aA = __builtin_amdgcn_mfma_f32_32x32x16_f16(af[t], bfA, zc, 0, 0, 0);
                const f32x16 aB = __builtin_amdgcn_mfma_f32_32x32x16_f16(af[t], bfB, zc, 0, 0, 0);
#pragma unroll
                for (int r = 0; r < 16; ++r)
                    rb[t][r] = fminf(fminf(aA[r], aB[r]), rb[t][r]);
            }
        }
    }

    // --- reduce row-mins across the 32 cols (lane bits 0..4) ---
#pragma unroll
    for (int t = 0; t < 2; ++t)
#pragma unroll
        for (int r = 0; r < 16; ++r) {
            float v = rb[t][r];
            v = fminf(v, __shfl_xor(v, 1, 64));
            v = fminf(v, __shfl_xor(v, 2, 64));
            v = fminf(v, __shfl_xor(v, 4, 64));
            v = fminf(v, __shfl_xor(v, 8, 64));
            v = fminf(v, __shfl_xor(v, 16, 64));
            rb[t][r] = v;
        }

    // C layout: col=lane&31, row=(r&3)+8*(r>>2)+4*(lane>>5)
    if (cl == 0) {
        float* rbase = partial + (((size_t)(pass * BATCH + b) * NPTS)
                     + rowblk * BN + w * 64) * 2 + colhalf;
#pragma unroll
        for (int t = 0; t < 2; ++t)
#pragma unroll
            for (int r = 0; r < 16; ++r) {
                const int rloc = (r & 3) + 8 * (r >> 2) + 4 * kh;
                rbase[(t * 32 + rloc) * 2] = rb[t][r];
            }
    }
}

// Stage 2: min the two col-half partials per query, sum -> 512 block sums
__global__ __launch_bounds__(256) void chamfer_reduce1(
    const float* __restrict__ partial, float* __restrict__ bsums)
{
    const int gid = blockIdx.x * 256 + threadIdx.x;   // one query per thread
    const float2 v = ((const float2*)partial)[gid];
    float m = fminf(v.x, v.y);

#pragma unroll
    for (int off = 32; off > 0; off >>= 1) m += __shfl_down(m, off, 64);

    __shared__ float wsum[4];
    const int lane = threadIdx.x & 63;
    const int wid  = threadIdx.x >> 6;
    if (lane == 0) wsum[wid] = m;
    __syncthreads();
    if (threadIdx.x == 0)
        bsums[blockIdx.x] = (wsum[0] + wsum[1]) + (wsum[2] + wsum[3]);
}

// Stage 3: sum 512 block sums, scale, write scalar
__global__ __launch_bounds__(512) void chamfer_reduce2(
    const float* __restrict__ bsums, float* __restrict__ out)
{
    float m = bsums[threadIdx.x];
#pragma unroll
    for (int off = 32; off > 0; off >>= 1) m += __shfl_down(m, off, 64);

    __shared__ float wsum[8];
    const int lane = threadIdx.x & 63;
    const int wid  = threadIdx.x >> 6;
    if (lane == 0) wsum[wid] = m;
    __syncthreads();
    if (threadIdx.x == 0) {
        float t = ((wsum[0] + wsum[1]) + (wsum[2] + wsum[3]))
                + ((wsum[4] + wsum[5]) + (wsum[6] + wsum[7]));
        out[0] = t * (1.0f / 65536.0f);
    }
}

extern "C" void kernel_launch(void* const* d_in, const int* in_sizes, int n_in,
                              void* d_out, int out_size, void* d_ws, size_t ws_size,
                              hipStream_t stream) {
    const float* preds = (const float*)d_in[0];   // [8, 8192, 3]
    const float* gts   = (const float*)d_in[1];   // [8, 8192, 3]
    float* out = (float*)d_out;

    float* partial = (float*)d_ws;   // 131072*2 floats = 1 MB, fully overwritten
    float* bsums   = (float*)((char*)d_ws + (size_t)NQ_TOT * 2 * sizeof(float));

    chamfer_mfma_kernel<<<1024, TPB, 0, stream>>>(preds, gts, partial);
    chamfer_reduce1<<<512, 256, 0, stream>>>(partial, bsums);
    chamfer_reduce2<<<1, 512, 0, stream>>>(bsums, out);
}